// Round 8
// baseline (274.807 us; speedup 1.0000x reference)
//
#include <hip/hip_runtime.h>
#include <hip/hip_fp16.h>

#define N_NODES 50000
#define N_EDGES 800000
#define NREL 32
#define NEG_SLOPE 0.2f
#define SCAN_NB ((N_NODES + 255) / 256)   // 196

// ---------------- CSR build ----------------
__global__ __launch_bounds__(256) void hist_kernel(const int* __restrict__ ei,
                                                   int* __restrict__ counts) {
    int e = blockIdx.x * 256 + threadIdx.x;
    if (e < N_EDGES) atomicAdd(&counts[ei[N_EDGES + e]], 1);
}

// block-level exclusive scan
__global__ __launch_bounds__(256) void scan1_kernel(const int* __restrict__ counts,
                                                    int* __restrict__ offsets,
                                                    int* __restrict__ blocksums) {
    __shared__ int sh[256];
    int tid = threadIdx.x;
    int i = blockIdx.x * 256 + tid;
    int v = (i < N_NODES) ? counts[i] : 0;
    sh[tid] = v;
    __syncthreads();
    #pragma unroll
    for (int off = 1; off < 256; off <<= 1) {
        int t = (tid >= off) ? sh[tid - off] : 0;
        __syncthreads();
        sh[tid] += t;
        __syncthreads();
    }
    if (i < N_NODES) offsets[i] = sh[tid] - v;
    if (tid == 255) blocksums[blockIdx.x] = sh[255];
}

__global__ __launch_bounds__(256) void scan2_kernel(int* __restrict__ blocksums,
                                                    int* __restrict__ blockoff) {
    __shared__ int sh[256];
    int tid = threadIdx.x;
    int v = (tid < SCAN_NB) ? blocksums[tid] : 0;
    sh[tid] = v;
    __syncthreads();
    #pragma unroll
    for (int off = 1; off < 256; off <<= 1) {
        int t = (tid >= off) ? sh[tid - off] : 0;
        __syncthreads();
        sh[tid] += t;
        __syncthreads();
    }
    if (tid < SCAN_NB) blockoff[tid] = sh[tid] - v;
}

__global__ __launch_bounds__(256) void scan3_kernel(int* __restrict__ offsets,
                                                    const int* __restrict__ blockoff,
                                                    int* __restrict__ cursor) {
    int i = blockIdx.x * 256 + threadIdx.x;
    if (i < N_NODES) {
        int o = offsets[i] + blockoff[blockIdx.x];
        offsets[i] = o;
        cursor[i] = o;
    }
}

// pack (src, type): src < 2^16, type < 2^5
__global__ __launch_bounds__(256) void scatter_kernel(const int* __restrict__ ei,
                                                      const int* __restrict__ etype,
                                                      int* __restrict__ cursor,
                                                      int* __restrict__ elist) {
    int e = blockIdx.x * 256 + threadIdx.x;
    if (e >= N_EDGES) return;
    int s = ei[e];
    int d = ei[N_EDGES + e];
    int t = etype[e];
    int pos = atomicAdd(&cursor[d], 1);
    elist[pos] = (s << 5) | t;
}

// ---------------- node transform: xh = x@W (fp16, [N][C][H] layout), a_src, a_dst ----------------
// Wave = head h (col = h*64+lane). (256,2): VGPR cap 256 so Wreg[64] is resident.
// 4-node pipeline: 4 independent FMA chains hide the uniform x s_load latency.
__global__ __launch_bounds__(256, 2) void node_xform(
    const float* __restrict__ x, const float* __restrict__ W,
    const float* __restrict__ att_src, const float* __restrict__ att_dst,
    __half* __restrict__ xh, float* __restrict__ a_src, float* __restrict__ a_dst)
{
    int tid = threadIdx.x;
    int lane = tid & 63;
    int h = tid >> 6;          // wave == head
    int col = h * 64 + lane;

    float Wreg[64];
    #pragma unroll
    for (int k = 0; k < 64; ++k) Wreg[k] = W[k * 256 + col];
    float asv = att_src[col];
    float adv = att_dst[col];

    for (int n = blockIdx.x * 4; n < N_NODES; n += gridDim.x * 4) {
        const float* __restrict__ x0 = x + (size_t)n * 64;
        float a0 = 0.f, a1 = 0.f, a2 = 0.f, a3 = 0.f;
        #pragma unroll
        for (int k = 0; k < 64; ++k) {
            float wk = Wreg[k];
            a0 = fmaf(x0[k], wk, a0);
            a1 = fmaf(x0[64 + k], wk, a1);
            a2 = fmaf(x0[128 + k], wk, a2);
            a3 = fmaf(x0[192 + k], wk, a3);
        }
        xh[(size_t)(n + 0) * 256 + lane * 4 + h] = __float2half(a0);
        xh[(size_t)(n + 1) * 256 + lane * 4 + h] = __float2half(a1);
        xh[(size_t)(n + 2) * 256 + lane * 4 + h] = __float2half(a2);
        xh[(size_t)(n + 3) * 256 + lane * 4 + h] = __float2half(a3);

        float s0 = a0 * asv, d0 = a0 * adv;
        float s1 = a1 * asv, d1 = a1 * adv;
        float s2 = a2 * asv, d2 = a2 * adv;
        float s3 = a3 * asv, d3 = a3 * adv;
        #pragma unroll
        for (int m = 32; m >= 1; m >>= 1) {
            s0 += __shfl_xor(s0, m); d0 += __shfl_xor(d0, m);
            s1 += __shfl_xor(s1, m); d1 += __shfl_xor(d1, m);
            s2 += __shfl_xor(s2, m); d2 += __shfl_xor(d2, m);
            s3 += __shfl_xor(s3, m); d3 += __shfl_xor(d3, m);
        }
        if (lane == 0) {
            a_src[(n + 0) * 4 + h] = s0; a_dst[(n + 0) * 4 + h] = d0;
            a_src[(n + 1) * 4 + h] = s1; a_dst[(n + 1) * 4 + h] = d1;
            a_src[(n + 2) * 4 + h] = s2; a_dst[(n + 2) * 4 + h] = d2;
            a_src[(n + 3) * 4 + h] = s3; a_dst[(n + 3) * 4 + h] = d3;
        }
    }
}

// ---------------- relation table: a_edge_r[r][h] ----------------
__global__ __launch_bounds__(64) void rel_kernel(
    const float* __restrict__ rel_emb, const float* __restrict__ W_e,
    const float* __restrict__ att_edge, float* __restrict__ a_edge_r)
{
    int r = blockIdx.x;
    int lane = threadIdx.x;
    int h = lane >> 4;
    int i16 = lane & 15;

    float rr = rel_emb[r * 64 + lane];
    float4 acc = {0.f, 0.f, 0.f, 0.f};
    #pragma unroll
    for (int k = 0; k < 64; ++k) {
        float rv = __shfl(rr, k);
        float4 wv = *(const float4*)(W_e + k * 256 + h * 64 + i16 * 4);
        acc.x += rv * wv.x; acc.y += rv * wv.y;
        acc.z += rv * wv.z; acc.w += rv * wv.w;
    }
    float4 aev = *(const float4*)(att_edge + h * 64 + i16 * 4);
    float ae = acc.x * aev.x + acc.y * aev.y + acc.z * aev.z + acc.w * aev.w;
    #pragma unroll
    for (int m = 8; m >= 1; m >>= 1) ae += __shfl_xor(ae, m);
    if (i16 == 0) a_edge_r[r * 4 + h] = ae;
}

// ---------------- fused aggregate (2 waves per dst node) ----------------
// warp pair (2p, 2p+1) co-own node d = blockIdx*2 + p; each wave processes half
// the edge list; per-lane partials merged through LDS, single denom butterfly.
__global__ __launch_bounds__(256) void aggregate(
    const int* __restrict__ offsets, const int* __restrict__ counts,
    const int* __restrict__ elist, const float* __restrict__ a_src,
    const float* __restrict__ a_dst, const float* __restrict__ a_edge_r,
    const __half* __restrict__ xh, const float* __restrict__ bias,
    float* __restrict__ out)
{
    __shared__ float4 exsh[4][64];
    __shared__ int    ssh[4][64];
    __shared__ float4 pnum[4][64];
    __shared__ float4 pden[4][64];

    int lane = threadIdx.x & 63;
    int warp = threadIdx.x >> 6;   // 0..3
    int pair = warp >> 1;          // node slot within block
    int half = warp & 1;           // which half of the edge list
    int d = blockIdx.x * 2 + pair; // grid = 25000 -> always < N_NODES

    int beg = offsets[d];
    int deg = counts[d];
    int h1 = (deg + 1) >> 1;
    int mybeg = beg + (half ? h1 : 0);
    int mydeg = half ? (deg - h1) : h1;

    float4 advec = ((const float4*)a_dst)[d];

    float n0 = 0.f, n1 = 0.f, n2 = 0.f, n3 = 0.f;
    float d0 = 0.f, d1 = 0.f, d2 = 0.f, d3 = 0.f;

    for (int base = 0; base < mydeg; base += 64) {
        int m = mydeg - base; if (m > 64) m = 64;

        float4 ev = make_float4(0.f, 0.f, 0.f, 0.f);
        int s = 0;
        if (lane < m) {
            int pk = elist[mybeg + base + lane];
            s = pk >> 5;
            int t = pk & 31;
            float4 as = ((const float4*)a_src)[s];
            float4 ae = ((const float4*)a_edge_r)[t];
            float b0 = as.x + advec.x + ae.x; b0 = b0 > 0.f ? b0 : NEG_SLOPE * b0;
            float b1 = as.y + advec.y + ae.y; b1 = b1 > 0.f ? b1 : NEG_SLOPE * b1;
            float b2 = as.z + advec.z + ae.z; b2 = b2 > 0.f ? b2 : NEG_SLOPE * b2;
            float b3 = as.w + advec.w + ae.w; b3 = b3 > 0.f ? b3 : NEG_SLOPE * b3;
            ev.x = __expf(b0); ev.y = __expf(b1);
            ev.z = __expf(b2); ev.w = __expf(b3);
        }
        d0 += ev.x; d1 += ev.y; d2 += ev.z; d3 += ev.w;
        exsh[warp][lane] = ev;   // wave-private rows; wave-synchronous RAW
        ssh[warp][lane]  = s;

        #pragma unroll 4
        for (int j = 0; j < m; ++j) {
            float4 e = exsh[warp][j];   // broadcast read (no conflict)
            int sj = ssh[warp][j];
            const __half2* __restrict__ xr =
                (const __half2*)(xh + (size_t)sj * 256 + lane * 4);
            __half2 p0 = xr[0], p1 = xr[1];
            float2 f0 = __half22float2(p0), f1 = __half22float2(p1);
            n0 = fmaf(e.x, f0.x, n0);
            n1 = fmaf(e.y, f0.y, n1);
            n2 = fmaf(e.z, f1.x, n2);
            n3 = fmaf(e.w, f1.y, n3);
        }
    }

    pnum[warp][lane] = make_float4(n0, n1, n2, n3);
    pden[warp][lane] = make_float4(d0, d1, d2, d3);
    __syncthreads();

    if (half == 0) {
        float4 on = pnum[warp + 1][lane];
        float4 od = pden[warp + 1][lane];
        n0 += on.x; n1 += on.y; n2 += on.z; n3 += on.w;
        d0 += od.x; d1 += od.y; d2 += od.z; d3 += od.w;

        #pragma unroll
        for (int msk = 32; msk >= 1; msk >>= 1) {
            d0 += __shfl_xor(d0, msk);
            d1 += __shfl_xor(d1, msk);
            d2 += __shfl_xor(d2, msk);
            d3 += __shfl_xor(d3, msk);
        }

        float r = 0.f;
        if (deg > 0)
            r = 0.25f * (n0 / d0 + n1 / d1 + n2 / d2 + n3 / d3);
        out[(size_t)d * 64 + lane] = r + bias[lane];
    }
}

extern "C" void kernel_launch(void* const* d_in, const int* in_sizes, int n_in,
                              void* d_out, int out_size, void* d_ws, size_t ws_size,
                              hipStream_t stream) {
    const float* x        = (const float*)d_in[0];
    const int*   ei       = (const int*)  d_in[1];
    const int*   etype    = (const int*)  d_in[2];
    const float* rel_emb  = (const float*)d_in[3];
    const float* W        = (const float*)d_in[4];
    const float* W_e      = (const float*)d_in[5];
    const float* att_src  = (const float*)d_in[6];
    const float* att_dst  = (const float*)d_in[7];
    const float* att_edge = (const float*)d_in[8];
    const float* bias     = (const float*)d_in[9];
    float* out = (float*)d_out;

    // workspace layout
    char* ws = (char*)d_ws;
    __half* xh      = (__half*)ws;                              // N*256 halfs = 25.6 MB
    char* p = ws + (size_t)N_NODES * 256 * 2;
    float* a_src    = (float*)p;              p += N_NODES * 4 * 4;
    float* a_dst    = (float*)p;              p += N_NODES * 4 * 4;
    float* a_edge_r = (float*)p;              p += NREL * 4 * 4;
    int*   counts   = (int*)p;                p += N_NODES * 4;
    int*   offsets  = (int*)p;                p += N_NODES * 4;
    int*   cursor   = (int*)p;                p += N_NODES * 4;
    int*   blocksums= (int*)p;                p += 256 * 4;
    int*   blockoff = (int*)p;                p += 256 * 4;
    int*   elist    = (int*)p;                p += (size_t)N_EDGES * 4;

    hipMemsetAsync(counts, 0, N_NODES * sizeof(int), stream);
    hist_kernel<<<(N_EDGES + 255) / 256, 256, 0, stream>>>(ei, counts);
    scan1_kernel<<<SCAN_NB, 256, 0, stream>>>(counts, offsets, blocksums);
    scan2_kernel<<<1, 256, 0, stream>>>(blocksums, blockoff);
    scan3_kernel<<<SCAN_NB, 256, 0, stream>>>(offsets, blockoff, cursor);
    scatter_kernel<<<(N_EDGES + 255) / 256, 256, 0, stream>>>(ei, etype, cursor, elist);
    node_xform<<<512, 256, 0, stream>>>(x, W, att_src, att_dst, xh, a_src, a_dst);
    rel_kernel<<<NREL, 64, 0, stream>>>(rel_emb, W_e, att_edge, a_edge_r);
    aggregate<<<N_NODES / 2, 256, 0, stream>>>(offsets, counts, elist, a_src,
                                               a_dst, a_edge_r, xh, bias, out);
}

// Round 9
// 226.243 us; speedup vs baseline: 1.2147x; 1.2147x over previous
//
#include <hip/hip_runtime.h>
#include <hip/hip_fp16.h>

#define N_NODES 50000
#define N_EDGES 800000
#define NREL 32
#define NEG_SLOPE 0.2f
#define SCAN_NB ((N_NODES + 255) / 256)   // 196

// ---------------- CSR build ----------------
__global__ __launch_bounds__(256) void hist_kernel(const int* __restrict__ ei,
                                                   int* __restrict__ counts) {
    int e = blockIdx.x * 256 + threadIdx.x;
    if (e < N_EDGES) atomicAdd(&counts[ei[N_EDGES + e]], 1);
}

// block-level exclusive scan
__global__ __launch_bounds__(256) void scan1_kernel(const int* __restrict__ counts,
                                                    int* __restrict__ offsets,
                                                    int* __restrict__ blocksums) {
    __shared__ int sh[256];
    int tid = threadIdx.x;
    int i = blockIdx.x * 256 + tid;
    int v = (i < N_NODES) ? counts[i] : 0;
    sh[tid] = v;
    __syncthreads();
    #pragma unroll
    for (int off = 1; off < 256; off <<= 1) {
        int t = (tid >= off) ? sh[tid - off] : 0;
        __syncthreads();
        sh[tid] += t;
        __syncthreads();
    }
    if (i < N_NODES) offsets[i] = sh[tid] - v;
    if (tid == 255) blocksums[blockIdx.x] = sh[255];
}

__global__ __launch_bounds__(256) void scan2_kernel(int* __restrict__ blocksums,
                                                    int* __restrict__ blockoff) {
    __shared__ int sh[256];
    int tid = threadIdx.x;
    int v = (tid < SCAN_NB) ? blocksums[tid] : 0;
    sh[tid] = v;
    __syncthreads();
    #pragma unroll
    for (int off = 1; off < 256; off <<= 1) {
        int t = (tid >= off) ? sh[tid - off] : 0;
        __syncthreads();
        sh[tid] += t;
        __syncthreads();
    }
    if (tid < SCAN_NB) blockoff[tid] = sh[tid] - v;
}

__global__ __launch_bounds__(256) void scan3_kernel(int* __restrict__ offsets,
                                                    const int* __restrict__ blockoff,
                                                    int* __restrict__ cursor) {
    int i = blockIdx.x * 256 + threadIdx.x;
    if (i < N_NODES) {
        int o = offsets[i] + blockoff[blockIdx.x];
        offsets[i] = o;
        cursor[i] = o;
    }
}

// pack (src, type): src < 2^16, type < 2^5
__global__ __launch_bounds__(256) void scatter_kernel(const int* __restrict__ ei,
                                                      const int* __restrict__ etype,
                                                      int* __restrict__ cursor,
                                                      int* __restrict__ elist) {
    int e = blockIdx.x * 256 + threadIdx.x;
    if (e >= N_EDGES) return;
    int s = ei[e];
    int d = ei[N_EDGES + e];
    int t = etype[e];
    int pos = atomicAdd(&cursor[d], 1);
    elist[pos] = (s << 5) | t;
}

// ---------------- node transform: xh = x@W (fp16, [N][C][H] layout), a_src, a_dst ----------------
// W staged ONCE per block into LDS (compiler can't un-allocate LDS, unlike Wreg).
// Lane owns 4 cols (c4=lane -> cols 4*lane..+3, all in head lane>>4).
// Per wave-iteration: 4 nodes; per k: 1 dense ds_read_b128 + 4 s_load x + 16 FMA.
__global__ __launch_bounds__(256, 2) void node_xform(
    const float* __restrict__ x, const float* __restrict__ W,
    const float* __restrict__ att_src, const float* __restrict__ att_dst,
    __half* __restrict__ xh, float* __restrict__ a_src, float* __restrict__ a_dst)
{
    __shared__ float4 Wl[64][64];   // [k][c4] = W[k][4c4..4c4+3], 64 KB
    int tid = threadIdx.x;
    int lane = tid & 63;
    int wv = tid >> 6;

    {   // stage W (64 KB, coalesced)
        const float4* Wg = (const float4*)W;
        float4* Wf = &Wl[0][0];
        #pragma unroll
        for (int j = 0; j < 16; ++j) Wf[tid + 256 * j] = Wg[tid + 256 * j];
    }
    __syncthreads();

    int c4 = lane;                 // float4 column group
    int h = lane >> 4;             // head of my 4 cols
    float4 asv = ((const float4*)att_src)[c4];
    float4 adv = ((const float4*)att_dst)[c4];

    for (int base = blockIdx.x * 16 + wv * 4; base < N_NODES; base += gridDim.x * 16) {
        const float* __restrict__ xr = x + (size_t)base * 64;  // 4 rows, wave-uniform
        float4 A0 = {0,0,0,0}, A1 = {0,0,0,0}, A2 = {0,0,0,0}, A3 = {0,0,0,0};
        #pragma unroll 8
        for (int k = 0; k < 64; ++k) {
            float4 wv4 = Wl[k][c4];
            float x0 = xr[k], x1 = xr[64 + k], x2 = xr[128 + k], x3 = xr[192 + k];
            A0.x = fmaf(x0, wv4.x, A0.x); A0.y = fmaf(x0, wv4.y, A0.y);
            A0.z = fmaf(x0, wv4.z, A0.z); A0.w = fmaf(x0, wv4.w, A0.w);
            A1.x = fmaf(x1, wv4.x, A1.x); A1.y = fmaf(x1, wv4.y, A1.y);
            A1.z = fmaf(x1, wv4.z, A1.z); A1.w = fmaf(x1, wv4.w, A1.w);
            A2.x = fmaf(x2, wv4.x, A2.x); A2.y = fmaf(x2, wv4.y, A2.y);
            A2.z = fmaf(x2, wv4.z, A2.z); A2.w = fmaf(x2, wv4.w, A2.w);
            A3.x = fmaf(x3, wv4.x, A3.x); A3.y = fmaf(x3, wv4.y, A3.y);
            A3.z = fmaf(x3, wv4.z, A3.z); A3.w = fmaf(x3, wv4.w, A3.w);
        }

        // xh store: [n][cw*4 + h], cw = (lane&15)*4 + j
        int cwb = (lane & 15) * 4;
        {
            size_t b = (size_t)(base + 0) * 256 + cwb * 4 + h;
            xh[b] = __float2half(A0.x); xh[b + 4] = __float2half(A0.y);
            xh[b + 8] = __float2half(A0.z); xh[b + 12] = __float2half(A0.w);
            b += 256;
            xh[b] = __float2half(A1.x); xh[b + 4] = __float2half(A1.y);
            xh[b + 8] = __float2half(A1.z); xh[b + 12] = __float2half(A1.w);
            b += 256;
            xh[b] = __float2half(A2.x); xh[b + 4] = __float2half(A2.y);
            xh[b + 8] = __float2half(A2.z); xh[b + 12] = __float2half(A2.w);
            b += 256;
            xh[b] = __float2half(A3.x); xh[b + 4] = __float2half(A3.y);
            xh[b + 8] = __float2half(A3.z); xh[b + 12] = __float2half(A3.w);
        }

        // a_src/a_dst: dot my 4 cols, then 16-lane butterfly (head-local)
        float s0 = A0.x*asv.x + A0.y*asv.y + A0.z*asv.z + A0.w*asv.w;
        float d0 = A0.x*adv.x + A0.y*adv.y + A0.z*adv.z + A0.w*adv.w;
        float s1 = A1.x*asv.x + A1.y*asv.y + A1.z*asv.z + A1.w*asv.w;
        float d1 = A1.x*adv.x + A1.y*adv.y + A1.z*adv.z + A1.w*adv.w;
        float s2 = A2.x*asv.x + A2.y*asv.y + A2.z*asv.z + A2.w*asv.w;
        float d2 = A2.x*adv.x + A2.y*adv.y + A2.z*adv.z + A2.w*adv.w;
        float s3 = A3.x*asv.x + A3.y*asv.y + A3.z*asv.z + A3.w*asv.w;
        float d3 = A3.x*adv.x + A3.y*adv.y + A3.z*adv.z + A3.w*adv.w;
        #pragma unroll
        for (int m = 1; m <= 8; m <<= 1) {
            s0 += __shfl_xor(s0, m); d0 += __shfl_xor(d0, m);
            s1 += __shfl_xor(s1, m); d1 += __shfl_xor(d1, m);
            s2 += __shfl_xor(s2, m); d2 += __shfl_xor(d2, m);
            s3 += __shfl_xor(s3, m); d3 += __shfl_xor(d3, m);
        }
        if ((lane & 15) == 0) {
            a_src[(base + 0) * 4 + h] = s0; a_dst[(base + 0) * 4 + h] = d0;
            a_src[(base + 1) * 4 + h] = s1; a_dst[(base + 1) * 4 + h] = d1;
            a_src[(base + 2) * 4 + h] = s2; a_dst[(base + 2) * 4 + h] = d2;
            a_src[(base + 3) * 4 + h] = s3; a_dst[(base + 3) * 4 + h] = d3;
        }
    }
}

// ---------------- relation table: a_edge_r[r][h] ----------------
__global__ __launch_bounds__(64) void rel_kernel(
    const float* __restrict__ rel_emb, const float* __restrict__ W_e,
    const float* __restrict__ att_edge, float* __restrict__ a_edge_r)
{
    int r = blockIdx.x;
    int lane = threadIdx.x;
    int h = lane >> 4;
    int i16 = lane & 15;

    float rr = rel_emb[r * 64 + lane];
    float4 acc = {0.f, 0.f, 0.f, 0.f};
    #pragma unroll
    for (int k = 0; k < 64; ++k) {
        float rv = __shfl(rr, k);
        float4 wv = *(const float4*)(W_e + k * 256 + h * 64 + i16 * 4);
        acc.x += rv * wv.x; acc.y += rv * wv.y;
        acc.z += rv * wv.z; acc.w += rv * wv.w;
    }
    float4 aev = *(const float4*)(att_edge + h * 64 + i16 * 4);
    float ae = acc.x * aev.x + acc.y * aev.y + acc.z * aev.z + acc.w * aev.w;
    #pragma unroll
    for (int m = 8; m >= 1; m >>= 1) ae += __shfl_xor(ae, m);
    if (i16 == 0) a_edge_r[r * 4 + h] = ae;
}

// ---------------- fused aggregate (2 waves per dst node) ----------------
__global__ __launch_bounds__(256) void aggregate(
    const int* __restrict__ offsets, const int* __restrict__ counts,
    const int* __restrict__ elist, const float* __restrict__ a_src,
    const float* __restrict__ a_dst, const float* __restrict__ a_edge_r,
    const __half* __restrict__ xh, const float* __restrict__ bias,
    float* __restrict__ out)
{
    __shared__ float4 exsh[4][64];
    __shared__ int    ssh[4][64];
    __shared__ float4 pnum[4][64];
    __shared__ float4 pden[4][64];

    int lane = threadIdx.x & 63;
    int warp = threadIdx.x >> 6;   // 0..3
    int pair = warp >> 1;          // node slot within block
    int half = warp & 1;           // which half of the edge list
    int d = blockIdx.x * 2 + pair;

    int beg = offsets[d];
    int deg = counts[d];
    int h1 = (deg + 1) >> 1;
    int mybeg = beg + (half ? h1 : 0);
    int mydeg = half ? (deg - h1) : h1;

    float4 advec = ((const float4*)a_dst)[d];

    float n0 = 0.f, n1 = 0.f, n2 = 0.f, n3 = 0.f;
    float d0 = 0.f, d1 = 0.f, d2 = 0.f, d3 = 0.f;

    for (int base = 0; base < mydeg; base += 64) {
        int m = mydeg - base; if (m > 64) m = 64;

        float4 ev = make_float4(0.f, 0.f, 0.f, 0.f);
        int s = 0;
        if (lane < m) {
            int pk = elist[mybeg + base + lane];
            s = pk >> 5;
            int t = pk & 31;
            float4 as = ((const float4*)a_src)[s];
            float4 ae = ((const float4*)a_edge_r)[t];
            float b0 = as.x + advec.x + ae.x; b0 = b0 > 0.f ? b0 : NEG_SLOPE * b0;
            float b1 = as.y + advec.y + ae.y; b1 = b1 > 0.f ? b1 : NEG_SLOPE * b1;
            float b2 = as.z + advec.z + ae.z; b2 = b2 > 0.f ? b2 : NEG_SLOPE * b2;
            float b3 = as.w + advec.w + ae.w; b3 = b3 > 0.f ? b3 : NEG_SLOPE * b3;
            ev.x = __expf(b0); ev.y = __expf(b1);
            ev.z = __expf(b2); ev.w = __expf(b3);
        }
        d0 += ev.x; d1 += ev.y; d2 += ev.z; d3 += ev.w;
        exsh[warp][lane] = ev;   // wave-private rows; wave-synchronous RAW
        ssh[warp][lane]  = s;

        #pragma unroll 4
        for (int j = 0; j < m; ++j) {
            float4 e = exsh[warp][j];   // broadcast read (no conflict)
            int sj = ssh[warp][j];
            const __half2* __restrict__ xr =
                (const __half2*)(xh + (size_t)sj * 256 + lane * 4);
            __half2 p0 = xr[0], p1 = xr[1];
            float2 f0 = __half22float2(p0), f1 = __half22float2(p1);
            n0 = fmaf(e.x, f0.x, n0);
            n1 = fmaf(e.y, f0.y, n1);
            n2 = fmaf(e.z, f1.x, n2);
            n3 = fmaf(e.w, f1.y, n3);
        }
    }

    pnum[warp][lane] = make_float4(n0, n1, n2, n3);
    pden[warp][lane] = make_float4(d0, d1, d2, d3);
    __syncthreads();

    if (half == 0) {
        float4 on = pnum[warp + 1][lane];
        float4 od = pden[warp + 1][lane];
        n0 += on.x; n1 += on.y; n2 += on.z; n3 += on.w;
        d0 += od.x; d1 += od.y; d2 += od.z; d3 += od.w;

        #pragma unroll
        for (int msk = 32; msk >= 1; msk >>= 1) {
            d0 += __shfl_xor(d0, msk);
            d1 += __shfl_xor(d1, msk);
            d2 += __shfl_xor(d2, msk);
            d3 += __shfl_xor(d3, msk);
        }

        float r = 0.f;
        if (deg > 0)
            r = 0.25f * (n0 / d0 + n1 / d1 + n2 / d2 + n3 / d3);
        out[(size_t)d * 64 + lane] = r + bias[lane];
    }
}

extern "C" void kernel_launch(void* const* d_in, const int* in_sizes, int n_in,
                              void* d_out, int out_size, void* d_ws, size_t ws_size,
                              hipStream_t stream) {
    const float* x        = (const float*)d_in[0];
    const int*   ei       = (const int*)  d_in[1];
    const int*   etype    = (const int*)  d_in[2];
    const float* rel_emb  = (const float*)d_in[3];
    const float* W        = (const float*)d_in[4];
    const float* W_e      = (const float*)d_in[5];
    const float* att_src  = (const float*)d_in[6];
    const float* att_dst  = (const float*)d_in[7];
    const float* att_edge = (const float*)d_in[8];
    const float* bias     = (const float*)d_in[9];
    float* out = (float*)d_out;

    // workspace layout
    char* ws = (char*)d_ws;
    __half* xh      = (__half*)ws;                              // N*256 halfs = 25.6 MB
    char* p = ws + (size_t)N_NODES * 256 * 2;
    float* a_src    = (float*)p;              p += N_NODES * 4 * 4;
    float* a_dst    = (float*)p;              p += N_NODES * 4 * 4;
    float* a_edge_r = (float*)p;              p += NREL * 4 * 4;
    int*   counts   = (int*)p;                p += N_NODES * 4;
    int*   offsets  = (int*)p;                p += N_NODES * 4;
    int*   cursor   = (int*)p;                p += N_NODES * 4;
    int*   blocksums= (int*)p;                p += 256 * 4;
    int*   blockoff = (int*)p;                p += 256 * 4;
    int*   elist    = (int*)p;                p += (size_t)N_EDGES * 4;

    hipMemsetAsync(counts, 0, N_NODES * sizeof(int), stream);
    hist_kernel<<<(N_EDGES + 255) / 256, 256, 0, stream>>>(ei, counts);
    scan1_kernel<<<SCAN_NB, 256, 0, stream>>>(counts, offsets, blocksums);
    scan2_kernel<<<1, 256, 0, stream>>>(blocksums, blockoff);
    scan3_kernel<<<SCAN_NB, 256, 0, stream>>>(offsets, blockoff, cursor);
    scatter_kernel<<<(N_EDGES + 255) / 256, 256, 0, stream>>>(ei, etype, cursor, elist);
    node_xform<<<512, 256, 0, stream>>>(x, W, att_src, att_dst, xh, a_src, a_dst);
    rel_kernel<<<NREL, 64, 0, stream>>>(rel_emb, W_e, att_edge, a_edge_r);
    aggregate<<<N_NODES / 2, 256, 0, stream>>>(offsets, counts, elist, a_src,
                                               a_dst, a_edge_r, xh, bias, out);
}